// Round 12
// baseline (342.610 us; speedup 1.0000x reference)
//
#include <hip/hip_runtime.h>
#include <hip/hip_bf16.h>
#include <stdint.h>

#define TEMP 0.01f

typedef __attribute__((ext_vector_type(8))) short short8;
typedef __attribute__((ext_vector_type(4))) float f32x4;
typedef __attribute__((ext_vector_type(2))) float f32x2;
typedef __attribute__((ext_vector_type(16))) float f32x16;

__device__ __forceinline__ ushort f2bf(float f) {
  union { float f; uint32_t u; } c; c.f = f;
  uint32_t u = c.u;
  uint32_t r = (u + 0x7FFFu + ((u >> 16) & 1u)) >> 16;
  return (ushort)r;
}
__device__ __forceinline__ float bf2f(ushort h) {
  union { uint32_t u; float f; } c; c.u = ((uint32_t)h) << 16;
  return c.f;
}

__device__ __forceinline__ void async16(void* lds, const void* g) {
  __builtin_amdgcn_global_load_lds(
      (const __attribute__((address_space(1))) uint32_t*)g,
      (__attribute__((address_space(3))) uint32_t*)lds,
      16, 0, 0);
}

// ---------------- fused convert kernel (x + weights + biases) ----------------
__global__ __launch_bounds__(256) void convert_all(
    const float* __restrict__ X, ushort* __restrict__ Xb,
    const float* __restrict__ Wq, const float* __restrict__ Wk, const float* __restrict__ Wv,
    const float* __restrict__ bq, const float* __restrict__ bk, const float* __restrict__ bv,
    const float* __restrict__ W1, const float* __restrict__ b1,
    ushort* __restrict__ wqkv, ushort* __restrict__ w1p,
    float* __restrict__ biasq, float* __restrict__ b1p) {
  int idx = blockIdx.x * 256 + threadIdx.x;
  int stride = gridDim.x * 256;
  for (int i = idx; i < 9682944; i += stride) {  // 50432*768/4
    float4 f = ((const float4*)X)[i];
    ushort4 u;
    u.x = f2bf(f.x); u.y = f2bf(f.y); u.z = f2bf(f.z); u.w = f2bf(f.w);
    ((ushort4*)Xb)[i] = u;
  }
  for (int i = idx; i < 2304 * 768; i += stride) {
    int row = i / 768;
    float v = (row < 768) ? Wq[i] : (row < 1536) ? Wk[i - 768 * 768] : Wv[i - 1536 * 768];
    wqkv[i] = f2bf(v);
  }
  for (int i = idx; i < 64 * 1536; i += stride) {
    int row = i / 1536;
    w1p[i] = f2bf(row < 60 ? W1[i] : 0.f);
  }
  for (int i = idx; i < 2304; i += stride)
    biasq[i] = (i < 768) ? bq[i] : (i < 1536) ? bk[i - 768] : bv[i - 1536];
  for (int i = idx; i < 64; i += stride)
    b1p[i] = (i < 60) ? b1[i] : 0.f;
}

// ---------------- QKV GEMM: persistent 8-phase 256x256, 32x32x16 MFMA ----------------
// R9 schedule skeleton (staging/vmcnt/barriers) UNCHANGED — verified 3x. This round:
// 16x16x32 -> 32x32x16 MFMA (2495 vs 2075 TF ubench => MFMA term 2484->2065 cyc/kt).
// Register-neutral: frags a[2][4]+b[2][4] = 64 VGPR (same), acc 4x2xf32x16 = 128 (same).
// Per-phase read pattern keeps the 12/4/8/0 shape. A/B layout: row=lane&31,
// k=8*(lane>>5)+j (K-doubling rule, matches our verified 16x16x32 mapping).
// C/D: col=lane&31, row=(reg&3)+8*(reg>>2)+4*(lane>>5) (guide m74/m101).
#define STAGE(LDSBASE, SRC, OFF)                                          \
  async16(smem + (LDSBASE) + ldsW, (SRC) + (OFF));                        \
  async16(smem + (LDSBASE) + 8192 + ldsW, (SRC) + 64 * 1536 + (OFF))

#define RD_A32(BASE, F0)                                                   \
  _Pragma("unroll") for (int fi = 0; fi < 2; ++fi)                         \
  _Pragma("unroll") for (int s = 0; s < 4; ++s)                            \
    a[fi][s] = *(const short8*)(smem + (BASE) + aR + ((F0) + fi) * 4096 + cS[s]);
#define RD_B32(BASE, G)                                                    \
  _Pragma("unroll") for (int s = 0; s < 4; ++s)                            \
    b[G][s] = *(const short8*)(smem + (BASE) + bR + (G) * 4096 + cS[s]);
#define MFQ32(F0, G)                                                       \
  _Pragma("unroll") for (int fi = 0; fi < 2; ++fi)                         \
  _Pragma("unroll") for (int s = 0; s < 4; ++s)                            \
    acc[(F0) + fi][G] = __builtin_amdgcn_mfma_f32_32x32x16_bf16(           \
        a[fi][s], b[G][s], acc[(F0) + fi][G], 0, 0, 0);

#define PH_OPEN                                          \
  __builtin_amdgcn_s_barrier();                          \
  asm volatile("s_waitcnt lgkmcnt(0)" ::: "memory");     \
  __builtin_amdgcn_s_setprio(1);
#define PH_CLOSE                                         \
  __builtin_amdgcn_s_setprio(0);                         \
  __builtin_amdgcn_s_barrier();

__device__ __forceinline__ void tilecoord(int orig, int& m0, int& n0) {
  // bijective XCD swizzle: nwg=1773, q=221, r=5 (verified R3)
  int xcd = orig & 7, idx = orig >> 3;
  int nw = (xcd < 5 ? xcd * 222 : 1110 + (xcd - 5) * 221) + idx;
  m0 = (nw / 9) * 256;
  n0 = (nw % 9) * 256;
}

__global__ __launch_bounds__(512, 1) void gemm_qkv(const ushort* __restrict__ Xb,
                                                   const ushort* __restrict__ Wb,
                                                   const float* __restrict__ bias,
                                                   ushort* __restrict__ QKV) {
  __shared__ char smem[131072];
  const int tid = threadIdx.x;
  const int lane = tid & 63;
  const int wv = tid >> 6;   // 0..7
  const int wr = wv >> 2;    // 0..1  (M strip of 128)
  const int wc = wv & 3;     // 0..3  (N strip of 64)
  const int l31 = lane & 31;
  const int bid = blockIdx.x;                 // 0..255
  const int ntiles = (1772 - bid) / 256 + 1;  // 7 for bid<237 else 6

  // staging source geometry (pre-swizzled; rule #21) — unchanged
  const int srow = tid >> 3;
  const int scol = (((tid & 7) ^ (srow & 7)) << 4);
  const int ldsW = wv << 10;

  // ds_read addressing for 32x32x16 fragments (static per thread)
  const int aR = (wr * 128 + l31) * 128;
  const int bR = (wc * 64 + l31) * 128;
  int cS[4];
#pragma unroll
  for (int s = 0; s < 4; ++s)
    cS[s] = (s * 32 + (lane >> 5) * 16) ^ ((lane & 7) << 4);

  const int AE = 0, AO = 32768, BE = 65536, BO = 98304;

  int m0, n0;
  tilecoord(bid, m0, n0);
  const char* aS = (const char*)Xb + (size_t)(m0 + srow) * 1536 + scol;
  const char* bS = (const char*)Wb + (size_t)(n0 + srow) * 1536 + scol;

  f32x16 acc[4][2] = {};
  short8 a[2][4], b[2][4];

  // prologue (once): tile0 kt0 -> buf0 (4 halves), kt1 A0 -> buf1
  STAGE(AE, aS, 0);
  STAGE(AE + 16384, aS + 128 * 1536, 0);
  STAGE(BE, bS, 0);
  STAGE(BE + 16384, bS + 128 * 1536, 0);
  STAGE(AO, aS, 128);
  asm volatile("s_waitcnt vmcnt(2)" ::: "memory");
  __builtin_amdgcn_s_barrier();

  for (int t = 0;; ++t) {
    const bool lastT = (t == ntiles - 1);
    int m0n = 0, n0n = 0;
    const char* aS2 = aS;
    const char* bS2 = bS;
    if (!lastT) {
      tilecoord(bid + 256 * (t + 1), m0n, n0n);
      aS2 = (const char*)Xb + (size_t)(m0n + srow) * 1536 + scol;
      bS2 = (const char*)Wb + (size_t)(n0n + srow) * 1536 + scol;
    }

    for (int i = 0; i < 6; ++i) {
      const int kb1 = i * 256 + 128;           // kt 2i+1 (in-tile always)
      const bool ib = (i == 5);                // boundary iter
      const bool stg = !(ib && lastT);         // stage kt+2/kt+3 at all?
      const char* pA = ib ? aS2 : aS;          // sources for kt 2i+2 / 2i+3
      const char* pB = ib ? bS2 : bS;
      const int kA = ib ? 0 : i * 256 + 256;

      // ---- p0: rd A f0-1 (8) + B g0 (4) from bufE; stage kt(2i+1) A1
      RD_A32(AE, 0); RD_B32(BE, 0);
      STAGE(AO + 16384, aS + 128 * 1536, kb1);
      PH_OPEN; MFQ32(0, 0); PH_CLOSE;
      // ---- p1: rd B g1 (4); stage kt(2i+1) B0
      RD_B32(BE, 1);
      STAGE(BO, bS, kb1);
      PH_OPEN; MFQ32(0, 1); PH_CLOSE;
      // ---- p2: rd A f2-3 (8); stage kt(2i+1) B1
      RD_A32(AE, 2);
      STAGE(BO + 16384, bS + 128 * 1536, kb1);
      PH_OPEN; MFQ32(2, 0); PH_CLOSE;
      // ---- p3: stage kt(2i+2) A0; MFMA Q(2,1); counted wait publishes buf1
      if (stg) { STAGE(AE, pA, kA); }
      PH_OPEN; MFQ32(2, 1);
      __builtin_amdgcn_s_setprio(0);
      if (stg) { asm volatile("s_waitcnt vmcnt(2)" ::: "memory"); }
      else     { asm volatile("s_waitcnt vmcnt(0)" ::: "memory"); }
      __builtin_amdgcn_s_barrier();
      // ---- p4: rd A f0-1 + B g0 from bufO; stage kt(2i+2) A1
      RD_A32(AO, 0); RD_B32(BO, 0);
      if (stg) { STAGE(AE + 16384, pA + 128 * 1536, kA); }
      PH_OPEN; MFQ32(0, 0); PH_CLOSE;
      // ---- p5: rd B g1; stage kt(2i+2) B0
      RD_B32(BO, 1);
      if (stg) { STAGE(BE, pB, kA); }
      PH_OPEN; MFQ32(0, 1); PH_CLOSE;
      // ---- p6: rd A f2-3; stage kt(2i+2) B1
      RD_A32(AO, 2);
      if (stg) { STAGE(BE + 16384, pB + 128 * 1536, kA); }
      PH_OPEN; MFQ32(2, 0); PH_CLOSE;
      // ---- p7: stage kt(2i+3) A0; MFMA Q(2,1); counted wait publishes buf0
      if (stg) { STAGE(AO, pA, kA + 128); }
      PH_OPEN; MFQ32(2, 1);
      __builtin_amdgcn_s_setprio(0);
      if (stg) { asm volatile("s_waitcnt vmcnt(2)" ::: "memory"); }
      __builtin_amdgcn_s_barrier();
    }

    // per-tile epilogue: C/D 32x32 layout col=lane&31, row=(reg&3)+8*(reg>>2)+4*(lane>>5)
#pragma unroll
    for (int f = 0; f < 4; ++f) {
#pragma unroll
      for (int g = 0; g < 2; ++g) {
        int col = n0 + wc * 64 + g * 32 + l31;
        float bs = bias[col];
#pragma unroll
        for (int q = 0; q < 4; ++q) {
          int rowb = m0 + wr * 128 + f * 32 + q * 8 + 4 * (lane >> 5);
#pragma unroll
          for (int rr = 0; rr < 4; ++rr)
            QKV[(size_t)(rowb + rr) * 2304 + col] = f2bf(acc[f][g][q * 4 + rr] + bs);
        }
      }
    }
    if (lastT) break;
#pragma unroll
    for (int f = 0; f < 4; ++f)
#pragma unroll
      for (int g = 0; g < 2; ++g)
#pragma unroll
        for (int e = 0; e < 16; ++e)
          acc[f][g][e] = 0.f;
    m0 = m0n; n0 = n0n; aS = aS2; bS = bS2;
  }
}

// ---------------- fused MLP: layer1 MFMA GEMM (BK=64, swizzled) + layers 2/3 from LDS ----------------
__global__ __launch_bounds__(256) void gemm_mlp(const ushort* __restrict__ QKV,
                                                const ushort* __restrict__ W1p,
                                                const float* __restrict__ b1p,
                                                const float* __restrict__ W2,
                                                const float* __restrict__ b2,
                                                const float* __restrict__ W3,
                                                const float* __restrict__ b3,
                                                float* __restrict__ SAMPLE) {
  __shared__ char smem[39704];
  float* sW2 = (float*)(smem + 24576);
  float* sW3 = (float*)(smem + 38976);
  float* sb2 = (float*)(smem + 39456);
  float* sb3 = (float*)(smem + 39696);
  const int tid = threadIdx.x;
  const int lane = tid & 63;
  const int wv = tid >> 6;
  const int p0 = blockIdx.x * 128;
  const int lmod = lane & 15, ldiv = lane >> 4;

  for (int i = tid; i < 3600; i += 256) sW2[i] = W2[i];
  for (int i = tid; i < 120; i += 256) sW3[i] = W3[i];
  if (tid < 60) sb2[tid] = b2[tid];
  if (tid < 2) sb3[tid] = b3[tid];

  f32x4 acc[2][4] = {};

  const int srw = lane >> 3;
  const int scol = (((lane & 7) ^ srw) << 4);
  const char* gA[4];
#pragma unroll
  for (int c = 0; c < 4; ++c) {
    int p = p0 + c * 32 + wv * 8 + srw;
    int gr = (p / 196) * 197 + 1 + (p % 196);
    gA[c] = (const char*)QKV + (size_t)gr * 4608 + scol;
  }
  const char* gB[2];
#pragma unroll
  for (int c = 0; c < 2; ++c) {
    int r = c * 32 + wv * 8 + srw;
    gB[c] = (const char*)W1p + (size_t)r * 3072 + scol;
  }

  const int offA0 = (wv * 32 + lmod) * 128;
  const int offA1 = (wv * 32 + 16 + lmod) * 128;
  const int cs0 = (ldiv * 16) ^ ((lmod & 7) << 4);
  const int cs1 = (64 + ldiv * 16) ^ ((lmod & 7) << 4);

  for (int k0 = 0; k0 < 1536; k0 += 64) {
    int kb = k0 * 2;
#pragma unroll
    for (int c = 0; c < 4; ++c)
      async16(smem + c * 4096 + wv * 1024, gA[c] + kb);
#pragma unroll
    for (int c = 0; c < 2; ++c)
      async16(smem + 16384 + c * 4096 + wv * 1024, gB[c] + kb);
    __syncthreads();

    short8 a[2][2], b[4][2];
    a[0][0] = *(const short8*)(smem + offA0 + cs0);
    a[0][1] = *(const short8*)(smem + offA0 + cs1);
    a[1][0] = *(const short8*)(smem + offA1 + cs0);
    a[1][1] = *(const short8*)(smem + offA1 + cs1);
#pragma unroll
    for (int j = 0; j < 4; ++j) {
      int ob = 16384 + (j * 16 + lmod) * 128;
      b[j][0] = *(const short8*)(smem + ob + cs0);
      b[j][1] = *(const short8*)(smem + ob + cs1);
    }
#pragma unroll
    for (int i = 0; i < 2; ++i)
#pragma unroll
      for (int j = 0; j < 4; ++j) {
        acc[i][j] = __builtin_amdgcn_mfma_f32_16x16x32_bf16(a[i][0], b[j][0], acc[i][j], 0, 0, 0);
        acc[i][j] = __builtin_amdgcn_mfma_f32_16x16x32_bf16(a[i][1], b[j][1], acc[i][j], 0, 0, 0);
      }
    __syncthreads();
  }

  // layer-1 epilogue -> LDS H tile [128][66] bf16 (staging area is dead now)
  ushort* Hs = (ushort*)smem;
#pragma unroll
  for (int i = 0; i < 2; ++i) {
    int lrow = wv * 32 + i * 16 + ldiv * 4;
#pragma unroll
    for (int j = 0; j < 4; ++j) {
      int col = j * 16 + lmod;
      float bs = b1p[col];
#pragma unroll
      for (int rr = 0; rr < 4; ++rr) {
        float v = fmaxf(acc[i][j][rr] + bs, 0.f);
        Hs[(lrow + rr) * 66 + col] = f2bf(v);
      }
    }
  }
  __syncthreads();

  // layers 2+3: 2 threads per position (30 output neurons each), combine via shfl
  const int plocal = tid >> 1;
  const int half = tid & 1;
  const uint32_t* hrow = (const uint32_t*)(Hs + plocal * 66);
  float h[60];
#pragma unroll
  for (int i = 0; i < 30; ++i) {
    uint32_t u = hrow[i];
    h[2 * i] = bf2f((ushort)(u & 0xffffu));
    h[2 * i + 1] = bf2f((ushort)(u >> 16));
  }
  float s0 = 0.f, s1 = 0.f;
  const int obase = half * 30;
  for (int oo = 0; oo < 30; ++oo) {
    int o = obase + oo;
    float a = sb2[o];
    const float4* wrow = (const float4*)(sW2 + o * 60);
#pragma unroll
    for (int k = 0; k < 15; ++k) {
      float4 w4 = wrow[k];
      a += h[4 * k] * w4.x + h[4 * k + 1] * w4.y + h[4 * k + 2] * w4.z + h[4 * k + 3] * w4.w;
    }
    a = fmaxf(a, 0.f);
    s0 += a * sW3[o];
    s1 += a * sW3[60 + o];
  }
  s0 += __shfl_xor(s0, 1, 64);
  s1 += __shfl_xor(s1, 1, 64);
  if (half == 0) {
    int p = p0 + plocal;  // < 50176 (392*128 exact)
    SAMPLE[2 * p]     = 1.f / (1.f + __expf(-(s0 + sb3[0])));
    SAMPLE[2 * p + 1] = 1.f / (1.f + __expf(-(s1 + sb3[1])));
  }
}

// ---------------- fused grid-sample + attention: one wave per output row ----------------
__global__ __launch_bounds__(256) void sample_attn(const ushort* __restrict__ QKV,
                                                   const float* __restrict__ SAMPLE,
                                                   float* __restrict__ OUT) {
  int tid = threadIdx.x, lane = tid & 63, wv = tid >> 6;
  // bijective XCD swizzle (12608 = 8*1576): same-batch blocks share an XCD L2
  int orig = blockIdx.x;
  int nw = (orig & 7) * 1576 + (orig >> 3);
  int pos = nw * 4 + wv;  // < 50432
  int b = pos / 197, s = pos % 197;

  const uint32_t* qrow = (const uint32_t*)(QKV + (size_t)pos * 2304);
  float qv[12];
#pragma unroll
  for (int j = 0; j < 6; ++j) {
    uint32_t u = qrow[lane + j * 64];
    qv[2 * j] = bf2f((ushort)(u & 0xffffu));
    qv[2 * j + 1] = bf2f((ushort)(u >> 16));
  }

  float sk[12], sv[12];
#pragma unroll
  for (int j = 0; j < 12; ++j) { sk[j] = 0.f; sv[j] = 0.f; }

  if (s == 0) {
#pragma unroll
    for (int j = 0; j < 12; ++j) { sk[j] = 1.f; sv[j] = 1.f; }
  } else {
    int g = s - 1;
    int t0 = 2 * g, t1 = 2 * g + 1;
    const float* smp = SAMPLE + (size_t)b * 392;
    float gx = (t0 < 196) ? smp[2 * t0] : smp[2 * (t0 - 196) + 1];
    float gy = (t1 < 196) ? smp[2 * t1] : smp[2 * (t1 - 196) + 1];
    float ix = ((gx + 1.f) * 14.f - 1.f) * 0.5f;
    float iy = ((gy + 1.f) * 14.f - 1.f) * 0.5f;
    float fx0 = floorf(ix), fy0 = floorf(iy);
    float wx1 = ix - fx0, wx0 = 1.f - wx1;
    float wy1 = iy - fy0, wy0 = 1.f - wy1;
    int x0 = (int)fx0, x1 = x0 + 1, y0 = (int)fy0, y1 = y0 + 1;
    float w[4] = {wy0 * wx0, wy0 * wx1, wy1 * wx0, wy1 * wx1};
    int xs[4] = {x0, x1, x0, x1};
    int ys[4] = {y0, y0, y1, y1};
#pragma unroll
    for (int c = 0; c < 4; ++c) {
      bool valid = (xs[c] >= 0) && (xs[c] <= 13) && (ys[c] >= 0) && (ys[c] <= 13);
      float wc = valid ? w[c] : 0.f;
      int xc = min(max(xs[c], 0), 13);
      int yc = min(max(ys[c], 0), 13);
      const uint32_t* krow =
          (const uint32_t*)(QKV + ((size_t)(b * 197 + 1 + yc * 14 + xc) * 2304 + 768));
      const uint32_t* vrow = krow + 384;
#pragma unroll
      for (int j = 0; j < 6; ++j) {
        uint32_t ku = krow[lane + j * 64];
        uint32_t vu = vrow[lane + j * 64];
        sk[2 * j]     += wc * bf2f((ushort)(ku & 0xffffu));
        sk[2 * j + 1] += wc * bf2f((ushort)(ku >> 16));
        sv[2 * j]     += wc * bf2f((ushort)(vu & 0xffffu));
        sv[2 * j + 1] += wc * bf2f((ushort)(vu >> 16));
      }
    }
  }

  float part = 0.f;
#pragma unroll
  for (int j = 0; j < 12; ++j) part += sk[j] * qv[j];
#pragma unroll
  for (int m = 1; m < 64; m <<= 1) part += __shfl_xor(part, m, 64);
  float sig = 1.f / (1.f + __expf(-TEMP * part));

  float* orow = OUT + (size_t)pos * 768;
#pragma unroll
  for (int j = 0; j < 6; ++j) {
    f32x2 o;
    o.x = sig * sv[2 * j];
    o.y = sig * sv[2 * j + 1];
    __builtin_nontemporal_store(o, (f32x2*)(orow + 2 * lane + 128 * j));
  }
}

extern "C" void kernel_launch(void* const* d_in, const int* in_sizes, int n_in,
                              void* d_out, int out_size, void* d_ws, size_t ws_size,
                              hipStream_t stream) {
  const float* x  = (const float*)d_in[0];
  const float* Wq = (const float*)d_in[2];
  const float* bq = (const float*)d_in[3];
  const float* Wk = (const float*)d_in[4];
  const float* bk = (const float*)d_in[5];
  const float* Wv = (const float*)d_in[6];
  const float* bv = (const float*)d_in[7];
  const float* W1 = (const float*)d_in[8];
  const float* b1 = (const float*)d_in[9];
  const float* W2 = (const float*)d_in[10];
  const float* b2 = (const float*)d_in[11];
  const float* W3 = (const float*)d_in[12];
  const float* b3 = (const float*)d_in[13];
  float* out = (float*)d_out;

  char* ws = (char*)d_ws;
  ushort* x_bf = (ushort*)ws;   ws += 77463552;   // 50432*768*2
  ushort* qkv = (ushort*)ws;    ws += 232390656;  // 50432*2304*2
  ushort* wqkv = (ushort*)ws;   ws += 3538944;    // 2304*768*2
  ushort* w1p = (ushort*)ws;    ws += 196608;     // 64*1536*2
  float* biasq = (float*)ws;    ws += 9216;       // 2304*4
  float* b1p = (float*)ws;      ws += 256;        // 64*4
  float* sample = (float*)ws;   ws += 401408;     // 50176*2*4

  convert_all<<<2048, 256, 0, stream>>>(x, x_bf, Wq, Wk, Wv, bq, bk, bv, W1, b1,
                                        wqkv, w1p, biasq, b1p);
  gemm_qkv<<<256, 512, 0, stream>>>(x_bf, wqkv, biasq, qkv);  // persistent, 32x32 MFMA
  gemm_mlp<<<392, 256, 0, stream>>>(qkv, w1p, b1p, W2, b2, W3, b3, sample);
  sample_attn<<<12608, 256, 0, stream>>>(qkv, sample, out);
}

// Round 13
// 336.674 us; speedup vs baseline: 1.0176x; 1.0176x over previous
//
#include <hip/hip_runtime.h>
#include <hip/hip_bf16.h>
#include <stdint.h>

#define TEMP 0.01f

typedef __attribute__((ext_vector_type(8))) short short8;
typedef __attribute__((ext_vector_type(4))) float f32x4;

__device__ __forceinline__ ushort f2bf(float f) {
  union { float f; uint32_t u; } c; c.f = f;
  uint32_t u = c.u;
  uint32_t r = (u + 0x7FFFu + ((u >> 16) & 1u)) >> 16;
  return (ushort)r;
}
__device__ __forceinline__ float bf2f(ushort h) {
  union { uint32_t u; float f; } c; c.u = ((uint32_t)h) << 16;
  return c.f;
}

__device__ __forceinline__ void async16(void* lds, const void* g) {
  __builtin_amdgcn_global_load_lds(
      (const __attribute__((address_space(1))) uint32_t*)g,
      (__attribute__((address_space(3))) uint32_t*)lds,
      16, 0, 0);
}

// ---------------- fused convert kernel (x + weights + biases) ----------------
__global__ __launch_bounds__(256) void convert_all(
    const float* __restrict__ X, ushort* __restrict__ Xb,
    const float* __restrict__ Wq, const float* __restrict__ Wk, const float* __restrict__ Wv,
    const float* __restrict__ bq, const float* __restrict__ bk, const float* __restrict__ bv,
    const float* __restrict__ W1, const float* __restrict__ b1,
    ushort* __restrict__ wqkv, ushort* __restrict__ w1p,
    float* __restrict__ biasq, float* __restrict__ b1p) {
  int idx = blockIdx.x * 256 + threadIdx.x;
  int stride = gridDim.x * 256;
  for (int i = idx; i < 9682944; i += stride) {  // 50432*768/4
    float4 f = ((const float4*)X)[i];
    ushort4 u;
    u.x = f2bf(f.x); u.y = f2bf(f.y); u.z = f2bf(f.z); u.w = f2bf(f.w);
    ((ushort4*)Xb)[i] = u;
  }
  for (int i = idx; i < 2304 * 768; i += stride) {
    int row = i / 768;
    float v = (row < 768) ? Wq[i] : (row < 1536) ? Wk[i - 768 * 768] : Wv[i - 1536 * 768];
    wqkv[i] = f2bf(v);
  }
  for (int i = idx; i < 64 * 1536; i += stride) {
    int row = i / 1536;
    w1p[i] = f2bf(row < 60 ? W1[i] : 0.f);
  }
  for (int i = idx; i < 2304; i += stride)
    biasq[i] = (i < 768) ? bq[i] : (i < 1536) ? bk[i - 768] : bv[i - 1536];
  for (int i = idx; i < 64; i += stride)
    b1p[i] = (i < 60) ? b1[i] : 0.f;
}

// ---------------- QKV GEMM: persistent 8-phase 256x256 (T1+T2+T3+T4+T5) ----------------
// EXACT R11 version (measured 186us, 920 TF, MfmaUtil 42%, 0 conflicts; verified 3x).
// R10 lesson: 128 arch VGPR + 128 acc = exactly the 256/wave cap at 2 waves/SIMD —
// any fragment growth spills. R12 lesson: 32x32x16 fragment reads bank-conflict
// (1.6e7) in ways not predictable offline. FROZEN.
#define STAGE(LDSBASE, SRC, OFF)                                          \
  async16(smem + (LDSBASE) + ldsW, (SRC) + (OFF));                        \
  async16(smem + (LDSBASE) + 8192 + ldsW, (SRC) + 64 * 1536 + (OFF))

#define RDA4(BASE, F0)                                                                   \
  _Pragma("unroll") for (int f = 0; f < 4; ++f) {                                        \
    a[f][0] = *(const short8*)(smem + (BASE) + aRow + ((F0) + f) * 2048 + c0);           \
    a[f][1] = *(const short8*)(smem + (BASE) + aRow + ((F0) + f) * 2048 + c1);           \
  }
#define RDB2(BASE, G0)                                                                   \
  _Pragma("unroll") for (int g = 0; g < 2; ++g) {                                        \
    b[(G0) + g][0] = *(const short8*)(smem + (BASE) + bRow + ((G0) + g) * 2048 + c0);    \
    b[(G0) + g][1] = *(const short8*)(smem + (BASE) + bRow + ((G0) + g) * 2048 + c1);    \
  }
#define MF16(F0, G0)                                                                     \
  _Pragma("unroll") for (int f = 0; f < 4; ++f)                                          \
  _Pragma("unroll") for (int g = 0; g < 2; ++g) {                                        \
    acc[(F0) + f][(G0) + g] = __builtin_amdgcn_mfma_f32_16x16x32_bf16(                   \
        a[f][0], b[(G0) + g][0], acc[(F0) + f][(G0) + g], 0, 0, 0);                      \
    acc[(F0) + f][(G0) + g] = __builtin_amdgcn_mfma_f32_16x16x32_bf16(                   \
        a[f][1], b[(G0) + g][1], acc[(F0) + f][(G0) + g], 0, 0, 0);                      \
  }
#define PH_OPEN                                          \
  __builtin_amdgcn_s_barrier();                          \
  asm volatile("s_waitcnt lgkmcnt(0)" ::: "memory");     \
  __builtin_amdgcn_s_setprio(1);
#define PH_CLOSE                                         \
  __builtin_amdgcn_s_setprio(0);                         \
  __builtin_amdgcn_s_barrier();

__device__ __forceinline__ void tilecoord(int orig, int& m0, int& n0) {
  // bijective XCD swizzle: nwg=1773, q=221, r=5 (verified R3)
  int xcd = orig & 7, idx = orig >> 3;
  int nw = (xcd < 5 ? xcd * 222 : 1110 + (xcd - 5) * 221) + idx;
  m0 = (nw / 9) * 256;
  n0 = (nw % 9) * 256;
}

__global__ __launch_bounds__(512, 1) void gemm_qkv(const ushort* __restrict__ Xb,
                                                   const ushort* __restrict__ Wb,
                                                   const float* __restrict__ bias,
                                                   ushort* __restrict__ QKV) {
  __shared__ char smem[131072];
  const int tid = threadIdx.x;
  const int lane = tid & 63;
  const int wv = tid >> 6;   // 0..7
  const int wr = wv >> 2;    // 0..1  (M strip of 128)
  const int wc = wv & 3;     // 0..3  (N strip of 64)
  const int lmod = lane & 15, ldiv = lane >> 4;
  const int bid = blockIdx.x;                 // 0..255
  const int ntiles = (1772 - bid) / 256 + 1;  // 7 for bid<237 else 6

  // staging source geometry (pre-swizzled; rule #21)
  const int srow = tid >> 3;
  const int scol = (((tid & 7) ^ (srow & 7)) << 4);
  const int ldsW = wv << 10;

  // ds_read addressing (static per thread)
  const int aRow = (wr * 128 + lmod) * 128;
  const int bRow = (wc * 64 + lmod) * 128;
  const int c0 = (ldiv * 16) ^ ((lmod & 7) << 4);
  const int c1 = (64 + ldiv * 16) ^ ((lmod & 7) << 4);

  const int AE = 0, AO = 32768, BE = 65536, BO = 98304;

  int m0, n0;
  tilecoord(bid, m0, n0);
  const char* aS = (const char*)Xb + (size_t)(m0 + srow) * 1536 + scol;
  const char* bS = (const char*)Wb + (size_t)(n0 + srow) * 1536 + scol;

  f32x4 acc[8][4] = {};

  // prologue (once): tile0 kt0 -> buf0 (4 halves), kt1 A0 -> buf1
  STAGE(AE, aS, 0);
  STAGE(AE + 16384, aS + 128 * 1536, 0);
  STAGE(BE, bS, 0);
  STAGE(BE + 16384, bS + 128 * 1536, 0);
  STAGE(AO, aS, 128);
  asm volatile("s_waitcnt vmcnt(2)" ::: "memory");
  __builtin_amdgcn_s_barrier();

  for (int t = 0;; ++t) {
    const bool lastT = (t == ntiles - 1);
    int m0n = 0, n0n = 0;
    const char* aS2 = aS;
    const char* bS2 = bS;
    if (!lastT) {
      tilecoord(bid + 256 * (t + 1), m0n, n0n);
      aS2 = (const char*)Xb + (size_t)(m0n + srow) * 1536 + scol;
      bS2 = (const char*)Wb + (size_t)(n0n + srow) * 1536 + scol;
    }

    for (int i = 0; i < 6; ++i) {
      const int kb1 = i * 256 + 128;           // kt 2i+1 (in-tile always)
      const bool ib = (i == 5);                // boundary iter
      const bool stg = !(ib && lastT);         // stage kt+2/kt+3 at all?
      const char* pA = ib ? aS2 : aS;          // sources for kt 2i+2 / 2i+3
      const char* pB = ib ? bS2 : bS;
      const int kA = ib ? 0 : i * 256 + 256;

      short8 a[4][2], b[4][2];
      // ---- p0: read buf0 A f0-3 + B g0-1; stage kt(2i+1) A1
      RDA4(AE, 0); RDB2(BE, 0);
      STAGE(AO + 16384, aS + 128 * 1536, kb1);
      PH_OPEN; MF16(0, 0); PH_CLOSE;
      // ---- p1: read buf0 B g2-3; stage kt(2i+1) B0
      RDB2(BE, 2);
      STAGE(BO, bS, kb1);
      PH_OPEN; MF16(0, 2); PH_CLOSE;
      // ---- p2: read buf0 A f4-7; stage kt(2i+1) B1
      RDA4(AE, 4);
      STAGE(BO + 16384, bS + 128 * 1536, kb1);
      PH_OPEN; MF16(4, 0); PH_CLOSE;
      // ---- p3: stage kt(2i+2) A0; MFMA Q11; counted wait publishes buf1
      if (stg) { STAGE(AE, pA, kA); }
      PH_OPEN; MF16(4, 2);
      __builtin_amdgcn_s_setprio(0);
      if (stg) { asm volatile("s_waitcnt vmcnt(2)" ::: "memory"); }
      else     { asm volatile("s_waitcnt vmcnt(0)" ::: "memory"); }
      __builtin_amdgcn_s_barrier();
      // ---- p4: read buf1 A f0-3 + B g0-1; stage kt(2i+2) A1
      RDA4(AO, 0); RDB2(BO, 0);
      if (stg) { STAGE(AE + 16384, pA + 128 * 1536, kA); }
      PH_OPEN; MF16(0, 0); PH_CLOSE;
      // ---- p5: read buf1 B g2-3; stage kt(2i+2) B0
      RDB2(BO, 2);
      if (stg) { STAGE(BE, pB, kA); }
      PH_OPEN; MF16(0, 2); PH_CLOSE;
      // ---- p6: read buf1 A f4-7; stage kt(2i+2) B1
      RDA4(AO, 4);
      if (stg) { STAGE(BE + 16384, pB + 128 * 1536, kA); }
      PH_OPEN; MF16(4, 0); PH_CLOSE;
      // ---- p7: stage kt(2i+3) A0; MFMA Q11; counted wait publishes buf0
      if (stg) { STAGE(AO, pA, kA + 128); }
      PH_OPEN; MF16(4, 2);
      __builtin_amdgcn_s_setprio(0);
      if (stg) { asm volatile("s_waitcnt vmcnt(2)" ::: "memory"); }
      __builtin_amdgcn_s_barrier();
    }

    // per-tile epilogue (global stores only; LDS untouched; buf0 for next tile
    // already staged at p3-p6 and published by p7's vmcnt+barrier)
#pragma unroll
    for (int f = 0; f < 8; ++f) {
      int row = m0 + wr * 128 + f * 16 + ldiv * 4;
#pragma unroll
      for (int g = 0; g < 4; ++g) {
        int col = n0 + wc * 64 + g * 16 + lmod;
        float bs = bias[col];
#pragma unroll
        for (int rr = 0; rr < 4; ++rr)
          QKV[(size_t)(row + rr) * 2304 + col] = f2bf(acc[f][g][rr] + bs);
      }
    }
    if (lastT) break;
#pragma unroll
    for (int f = 0; f < 8; ++f)
#pragma unroll
      for (int g = 0; g < 4; ++g)
        acc[f][g] = f32x4{0.f, 0.f, 0.f, 0.f};
    m0 = m0n; n0 = n0n; aS = aS2; bS = bS2;
  }
}

// ---------------- fused MLP: layer1 MFMA GEMM (BK=64, swizzled) + layers 2/3 from LDS ----------------
__global__ __launch_bounds__(256) void gemm_mlp(const ushort* __restrict__ QKV,
                                                const ushort* __restrict__ W1p,
                                                const float* __restrict__ b1p,
                                                const float* __restrict__ W2,
                                                const float* __restrict__ b2,
                                                const float* __restrict__ W3,
                                                const float* __restrict__ b3,
                                                float* __restrict__ SAMPLE) {
  __shared__ char smem[39704];
  float* sW2 = (float*)(smem + 24576);
  float* sW3 = (float*)(smem + 38976);
  float* sb2 = (float*)(smem + 39456);
  float* sb3 = (float*)(smem + 39696);
  const int tid = threadIdx.x;
  const int lane = tid & 63;
  const int wv = tid >> 6;
  const int p0 = blockIdx.x * 128;
  const int lmod = lane & 15, ldiv = lane >> 4;

  for (int i = tid; i < 3600; i += 256) sW2[i] = W2[i];
  for (int i = tid; i < 120; i += 256) sW3[i] = W3[i];
  if (tid < 60) sb2[tid] = b2[tid];
  if (tid < 2) sb3[tid] = b3[tid];

  f32x4 acc[2][4] = {};

  const int srw = lane >> 3;
  const int scol = (((lane & 7) ^ srw) << 4);
  const char* gA[4];
#pragma unroll
  for (int c = 0; c < 4; ++c) {
    int p = p0 + c * 32 + wv * 8 + srw;
    int gr = (p / 196) * 197 + 1 + (p % 196);
    gA[c] = (const char*)QKV + (size_t)gr * 4608 + scol;
  }
  const char* gB[2];
#pragma unroll
  for (int c = 0; c < 2; ++c) {
    int r = c * 32 + wv * 8 + srw;
    gB[c] = (const char*)W1p + (size_t)r * 3072 + scol;
  }

  const int offA0 = (wv * 32 + lmod) * 128;
  const int offA1 = (wv * 32 + 16 + lmod) * 128;
  const int cs0 = (ldiv * 16) ^ ((lmod & 7) << 4);
  const int cs1 = (64 + ldiv * 16) ^ ((lmod & 7) << 4);

  for (int k0 = 0; k0 < 1536; k0 += 64) {
    int kb = k0 * 2;
#pragma unroll
    for (int c = 0; c < 4; ++c)
      async16(smem + c * 4096 + wv * 1024, gA[c] + kb);
#pragma unroll
    for (int c = 0; c < 2; ++c)
      async16(smem + 16384 + c * 4096 + wv * 1024, gB[c] + kb);
    __syncthreads();

    short8 a[2][2], b[4][2];
    a[0][0] = *(const short8*)(smem + offA0 + cs0);
    a[0][1] = *(const short8*)(smem + offA0 + cs1);
    a[1][0] = *(const short8*)(smem + offA1 + cs0);
    a[1][1] = *(const short8*)(smem + offA1 + cs1);
#pragma unroll
    for (int j = 0; j < 4; ++j) {
      int ob = 16384 + (j * 16 + lmod) * 128;
      b[j][0] = *(const short8*)(smem + ob + cs0);
      b[j][1] = *(const short8*)(smem + ob + cs1);
    }
#pragma unroll
    for (int i = 0; i < 2; ++i)
#pragma unroll
      for (int j = 0; j < 4; ++j) {
        acc[i][j] = __builtin_amdgcn_mfma_f32_16x16x32_bf16(a[i][0], b[j][0], acc[i][j], 0, 0, 0);
        acc[i][j] = __builtin_amdgcn_mfma_f32_16x16x32_bf16(a[i][1], b[j][1], acc[i][j], 0, 0, 0);
      }
    __syncthreads();
  }

  // layer-1 epilogue -> LDS H tile [128][66] bf16 (staging area is dead now)
  ushort* Hs = (ushort*)smem;
#pragma unroll
  for (int i = 0; i < 2; ++i) {
    int lrow = wv * 32 + i * 16 + ldiv * 4;
#pragma unroll
    for (int j = 0; j < 4; ++j) {
      int col = j * 16 + lmod;
      float bs = b1p[col];
#pragma unroll
      for (int rr = 0; rr < 4; ++rr) {
        float v = fmaxf(acc[i][j][rr] + bs, 0.f);
        Hs[(lrow + rr) * 66 + col] = f2bf(v);
      }
    }
  }
  __syncthreads();

  // layers 2+3: 2 threads per position (30 output neurons each), combine via shfl
  const int plocal = tid >> 1;
  const int half = tid & 1;
  const uint32_t* hrow = (const uint32_t*)(Hs + plocal * 66);
  float h[60];
#pragma unroll
  for (int i = 0; i < 30; ++i) {
    uint32_t u = hrow[i];
    h[2 * i] = bf2f((ushort)(u & 0xffffu));
    h[2 * i + 1] = bf2f((ushort)(u >> 16));
  }
  float s0 = 0.f, s1 = 0.f;
  const int obase = half * 30;
  for (int oo = 0; oo < 30; ++oo) {
    int o = obase + oo;
    float a = sb2[o];
    const float4* wrow = (const float4*)(sW2 + o * 60);
#pragma unroll
    for (int k = 0; k < 15; ++k) {
      float4 w4 = wrow[k];
      a += h[4 * k] * w4.x + h[4 * k + 1] * w4.y + h[4 * k + 2] * w4.z + h[4 * k + 3] * w4.w;
    }
    a = fmaxf(a, 0.f);
    s0 += a * sW3[o];
    s1 += a * sW3[60 + o];
  }
  s0 += __shfl_xor(s0, 1, 64);
  s1 += __shfl_xor(s1, 1, 64);
  if (half == 0) {
    int p = p0 + plocal;  // < 50176 (392*128 exact)
    SAMPLE[2 * p]     = 1.f / (1.f + __expf(-(s0 + sb3[0])));
    SAMPLE[2 * p + 1] = 1.f / (1.f + __expf(-(s1 + sb3[1])));
  }
}

// ---------------- fused grid-sample + attention: one wave per output row ----------------
// R13: vectorized — uint2 (8B/lane) row loads, 3 passes instead of 6; float4
// nontemporal stores (16B/lane), 3 instead of 6. Lane layout: pass j covers
// cols [4*lane + 256*j .. +3].
__global__ __launch_bounds__(256) void sample_attn(const ushort* __restrict__ QKV,
                                                   const float* __restrict__ SAMPLE,
                                                   float* __restrict__ OUT) {
  int tid = threadIdx.x, lane = tid & 63, wv = tid >> 6;
  // bijective XCD swizzle (12608 = 8*1576): same-batch blocks share an XCD L2
  int orig = blockIdx.x;
  int nw = (orig & 7) * 1576 + (orig >> 3);
  int pos = nw * 4 + wv;  // < 50432
  int b = pos / 197, s = pos % 197;

  const uint2* qrow = (const uint2*)(QKV + (size_t)pos * 2304);
  float qv[12];
#pragma unroll
  for (int j = 0; j < 3; ++j) {
    uint2 u = qrow[lane + j * 64];
    qv[4 * j]     = bf2f((ushort)(u.x & 0xffffu));
    qv[4 * j + 1] = bf2f((ushort)(u.x >> 16));
    qv[4 * j + 2] = bf2f((ushort)(u.y & 0xffffu));
    qv[4 * j + 3] = bf2f((ushort)(u.y >> 16));
  }

  float sk[12], sv[12];
#pragma unroll
  for (int j = 0; j < 12; ++j) { sk[j] = 0.f; sv[j] = 0.f; }

  if (s == 0) {
#pragma unroll
    for (int j = 0; j < 12; ++j) { sk[j] = 1.f; sv[j] = 1.f; }
  } else {
    int g = s - 1;
    int t0 = 2 * g, t1 = 2 * g + 1;
    const float* smp = SAMPLE + (size_t)b * 392;
    float gx = (t0 < 196) ? smp[2 * t0] : smp[2 * (t0 - 196) + 1];
    float gy = (t1 < 196) ? smp[2 * t1] : smp[2 * (t1 - 196) + 1];
    float ix = ((gx + 1.f) * 14.f - 1.f) * 0.5f;
    float iy = ((gy + 1.f) * 14.f - 1.f) * 0.5f;
    float fx0 = floorf(ix), fy0 = floorf(iy);
    float wx1 = ix - fx0, wx0 = 1.f - wx1;
    float wy1 = iy - fy0, wy0 = 1.f - wy1;
    int x0 = (int)fx0, x1 = x0 + 1, y0 = (int)fy0, y1 = y0 + 1;
    float w[4] = {wy0 * wx0, wy0 * wx1, wy1 * wx0, wy1 * wx1};
    int xs[4] = {x0, x1, x0, x1};
    int ys[4] = {y0, y0, y1, y1};
#pragma unroll
    for (int c = 0; c < 4; ++c) {
      bool valid = (xs[c] >= 0) && (xs[c] <= 13) && (ys[c] >= 0) && (ys[c] <= 13);
      float wc = valid ? w[c] : 0.f;
      int xc = min(max(xs[c], 0), 13);
      int yc = min(max(ys[c], 0), 13);
      const uint2* krow =
          (const uint2*)(QKV + ((size_t)(b * 197 + 1 + yc * 14 + xc) * 2304 + 768));
      const uint2* vrow = krow + 192;  // +768 bf16 = 192 uint2
#pragma unroll
      for (int j = 0; j < 3; ++j) {
        uint2 ku = krow[lane + j * 64];
        uint2 vu = vrow[lane + j * 64];
        sk[4 * j]     += wc * bf2f((ushort)(ku.x & 0xffffu));
        sk[4 * j + 1] += wc * bf2f((ushort)(ku.x >> 16));
        sk[4 * j + 2] += wc * bf2f((ushort)(ku.y & 0xffffu));
        sk[4 * j + 3] += wc * bf2f((ushort)(ku.y >> 16));
        sv[4 * j]     += wc * bf2f((ushort)(vu.x & 0xffffu));
        sv[4 * j + 1] += wc * bf2f((ushort)(vu.x >> 16));
        sv[4 * j + 2] += wc * bf2f((ushort)(vu.y & 0xffffu));
        sv[4 * j + 3] += wc * bf2f((ushort)(vu.y >> 16));
      }
    }
  }

  float part = 0.f;
#pragma unroll
  for (int j = 0; j < 12; ++j) part += sk[j] * qv[j];
#pragma unroll
  for (int m = 1; m < 64; m <<= 1) part += __shfl_xor(part, m, 64);
  float sig = 1.f / (1.f + __expf(-TEMP * part));

  float* orow = OUT + (size_t)pos * 768;
#pragma unroll
  for (int j = 0; j < 3; ++j) {
    f32x4 o;
    o.x = sig * sv[4 * j];
    o.y = sig * sv[4 * j + 1];
    o.z = sig * sv[4 * j + 2];
    o.w = sig * sv[4 * j + 3];
    __builtin_nontemporal_store(o, (f32x4*)(orow + 4 * lane + 256 * j));
  }
}

extern "C" void kernel_launch(void* const* d_in, const int* in_sizes, int n_in,
                              void* d_out, int out_size, void* d_ws, size_t ws_size,
                              hipStream_t stream) {
  const float* x  = (const float*)d_in[0];
  const float* Wq = (const float*)d_in[2];
  const float* bq = (const float*)d_in[3];
  const float* Wk = (const float*)d_in[4];
  const float* bk = (const float*)d_in[5];
  const float* Wv = (const float*)d_in[6];
  const float* bv = (const float*)d_in[7];
  const float* W1 = (const float*)d_in[8];
  const float* b1 = (const float*)d_in[9];
  const float* W2 = (const float*)d_in[10];
  const float* b2 = (const float*)d_in[11];
  const float* W3 = (const float*)d_in[12];
  const float* b3 = (const float*)d_in[13];
  float* out = (float*)d_out;

  char* ws = (char*)d_ws;
  ushort* x_bf = (ushort*)ws;   ws += 77463552;   // 50432*768*2
  ushort* qkv = (ushort*)ws;    ws += 232390656;  // 50432*2304*2
  ushort* wqkv = (ushort*)ws;   ws += 3538944;    // 2304*768*2
  ushort* w1p = (ushort*)ws;    ws += 196608;     // 64*1536*2
  float* biasq = (float*)ws;    ws += 9216;       // 2304*4
  float* b1p = (float*)ws;      ws += 256;        // 64*4
  float* sample = (float*)ws;   ws += 401408;     // 50176*2*4

  convert_all<<<2048, 256, 0, stream>>>(x, x_bf, Wq, Wk, Wv, bq, bk, bv, W1, b1,
                                        wqkv, w1p, biasq, b1p);
  gemm_qkv<<<256, 512, 0, stream>>>(x_bf, wqkv, biasq, qkv);  // persistent (R11-exact)
  gemm_mlp<<<392, 256, 0, stream>>>(qkv, w1p, b1p, W2, b2, W3, b3, sample);
  sample_attn<<<12608, 256, 0, stream>>>(qkv, sample, out);
}

// Round 14
// 328.562 us; speedup vs baseline: 1.0428x; 1.0247x over previous
//
#include <hip/hip_runtime.h>
#include <hip/hip_bf16.h>
#include <stdint.h>

#define TEMP 0.01f

typedef __attribute__((ext_vector_type(8))) short short8;
typedef __attribute__((ext_vector_type(4))) float f32x4;
typedef __attribute__((ext_vector_type(2))) float f32x2;

__device__ __forceinline__ ushort f2bf(float f) {
  union { float f; uint32_t u; } c; c.f = f;
  uint32_t u = c.u;
  uint32_t r = (u + 0x7FFFu + ((u >> 16) & 1u)) >> 16;
  return (ushort)r;
}
__device__ __forceinline__ float bf2f(ushort h) {
  union { uint32_t u; float f; } c; c.u = ((uint32_t)h) << 16;
  return c.f;
}

__device__ __forceinline__ void async16(void* lds, const void* g) {
  __builtin_amdgcn_global_load_lds(
      (const __attribute__((address_space(1))) uint32_t*)g,
      (__attribute__((address_space(3))) uint32_t*)lds,
      16, 0, 0);
}

// ---------------- fused convert kernel (x + weights + biases) ----------------
__global__ __launch_bounds__(256) void convert_all(
    const float* __restrict__ X, ushort* __restrict__ Xb,
    const float* __restrict__ Wq, const float* __restrict__ Wk, const float* __restrict__ Wv,
    const float* __restrict__ bq, const float* __restrict__ bk, const float* __restrict__ bv,
    const float* __restrict__ W1, const float* __restrict__ b1,
    ushort* __restrict__ wqkv, ushort* __restrict__ w1p,
    float* __restrict__ biasq, float* __restrict__ b1p) {
  int idx = blockIdx.x * 256 + threadIdx.x;
  int stride = gridDim.x * 256;
  for (int i = idx; i < 9682944; i += stride) {  // 50432*768/4
    float4 f = ((const float4*)X)[i];
    ushort4 u;
    u.x = f2bf(f.x); u.y = f2bf(f.y); u.z = f2bf(f.z); u.w = f2bf(f.w);
    ((ushort4*)Xb)[i] = u;
  }
  for (int i = idx; i < 2304 * 768; i += stride) {
    int row = i / 768;
    float v = (row < 768) ? Wq[i] : (row < 1536) ? Wk[i - 768 * 768] : Wv[i - 1536 * 768];
    wqkv[i] = f2bf(v);
  }
  for (int i = idx; i < 64 * 1536; i += stride) {
    int row = i / 1536;
    w1p[i] = f2bf(row < 60 ? W1[i] : 0.f);
  }
  for (int i = idx; i < 2304; i += stride)
    biasq[i] = (i < 768) ? bq[i] : (i < 1536) ? bk[i - 768] : bv[i - 1536];
  for (int i = idx; i < 64; i += stride)
    b1p[i] = (i < 60) ? b1[i] : 0.f;
}

// ---------------- QKV GEMM: persistent 8-phase 256x256 (T1+T2+T3+T4+T5) ----------------
// R11 schedule + R14 change: close-barriers dropped at p0/p1/p4/p5 (12 instead of 16
// barriers/kt). Audit: those closes are not WAR-load-bearing — their read regions are
// restaged >=2 open-barriers later (AE@p3, BE@p5, AO@p7, BO@next-p1), and each open
// barrier's per-wave lgkmcnt(0) confirms reads before any restage. p2/p6 closes ARE
// load-bearing (region restaged in the immediately following phase) and remain.
// vmcnt publish ledger is program-order-based — unchanged.
// R10 lesson: 128 arch + 128 acc VGPR = exactly the 2-waves/SIMD cap; no frag growth.
// R12 lesson: 32x32x16 frag reads bank-conflict unpredictably. Shape stays 16x16x32.
#define STAGE(LDSBASE, SRC, OFF)                                          \
  async16(smem + (LDSBASE) + ldsW, (SRC) + (OFF));                        \
  async16(smem + (LDSBASE) + 8192 + ldsW, (SRC) + 64 * 1536 + (OFF))

#define RDA4(BASE, F0)                                                                   \
  _Pragma("unroll") for (int f = 0; f < 4; ++f) {                                        \
    a[f][0] = *(const short8*)(smem + (BASE) + aRow + ((F0) + f) * 2048 + c0);           \
    a[f][1] = *(const short8*)(smem + (BASE) + aRow + ((F0) + f) * 2048 + c1);           \
  }
#define RDB2(BASE, G0)                                                                   \
  _Pragma("unroll") for (int g = 0; g < 2; ++g) {                                        \
    b[(G0) + g][0] = *(const short8*)(smem + (BASE) + bRow + ((G0) + g) * 2048 + c0);    \
    b[(G0) + g][1] = *(const short8*)(smem + (BASE) + bRow + ((G0) + g) * 2048 + c1);    \
  }
#define MF16(F0, G0)                                                                     \
  _Pragma("unroll") for (int f = 0; f < 4; ++f)                                          \
  _Pragma("unroll") for (int g = 0; g < 2; ++g) {                                        \
    acc[(F0) + f][(G0) + g] = __builtin_amdgcn_mfma_f32_16x16x32_bf16(                   \
        a[f][0], b[(G0) + g][0], acc[(F0) + f][(G0) + g], 0, 0, 0);                      \
    acc[(F0) + f][(G0) + g] = __builtin_amdgcn_mfma_f32_16x16x32_bf16(                   \
        a[f][1], b[(G0) + g][1], acc[(F0) + f][(G0) + g], 0, 0, 0);                      \
  }
#define PH_OPEN                                          \
  __builtin_amdgcn_s_barrier();                          \
  asm volatile("s_waitcnt lgkmcnt(0)" ::: "memory");     \
  __builtin_amdgcn_s_setprio(1);
#define PH_CLOSE                                         \
  __builtin_amdgcn_s_setprio(0);                         \
  __builtin_amdgcn_s_barrier();
#define PH_CLOSE_NB                                      \
  __builtin_amdgcn_s_setprio(0);

__device__ __forceinline__ void tilecoord(int orig, int& m0, int& n0) {
  // bijective XCD swizzle: nwg=1773, q=221, r=5 (verified R3)
  int xcd = orig & 7, idx = orig >> 3;
  int nw = (xcd < 5 ? xcd * 222 : 1110 + (xcd - 5) * 221) + idx;
  m0 = (nw / 9) * 256;
  n0 = (nw % 9) * 256;
}

__global__ __launch_bounds__(512, 1) void gemm_qkv(const ushort* __restrict__ Xb,
                                                   const ushort* __restrict__ Wb,
                                                   const float* __restrict__ bias,
                                                   ushort* __restrict__ QKV) {
  __shared__ char smem[131072];
  const int tid = threadIdx.x;
  const int lane = tid & 63;
  const int wv = tid >> 6;   // 0..7
  const int wr = wv >> 2;    // 0..1  (M strip of 128)
  const int wc = wv & 3;     // 0..3  (N strip of 64)
  const int lmod = lane & 15, ldiv = lane >> 4;
  const int bid = blockIdx.x;                 // 0..255
  const int ntiles = (1772 - bid) / 256 + 1;  // 7 for bid<237 else 6

  // staging source geometry (pre-swizzled; rule #21)
  const int srow = tid >> 3;
  const int scol = (((tid & 7) ^ (srow & 7)) << 4);
  const int ldsW = wv << 10;

  // ds_read addressing (static per thread)
  const int aRow = (wr * 128 + lmod) * 128;
  const int bRow = (wc * 64 + lmod) * 128;
  const int c0 = (ldiv * 16) ^ ((lmod & 7) << 4);
  const int c1 = (64 + ldiv * 16) ^ ((lmod & 7) << 4);

  const int AE = 0, AO = 32768, BE = 65536, BO = 98304;

  int m0, n0;
  tilecoord(bid, m0, n0);
  const char* aS = (const char*)Xb + (size_t)(m0 + srow) * 1536 + scol;
  const char* bS = (const char*)Wb + (size_t)(n0 + srow) * 1536 + scol;

  f32x4 acc[8][4] = {};

  // prologue (once): tile0 kt0 -> buf0 (4 halves), kt1 A0 -> buf1
  STAGE(AE, aS, 0);
  STAGE(AE + 16384, aS + 128 * 1536, 0);
  STAGE(BE, bS, 0);
  STAGE(BE + 16384, bS + 128 * 1536, 0);
  STAGE(AO, aS, 128);
  asm volatile("s_waitcnt vmcnt(2)" ::: "memory");
  __builtin_amdgcn_s_barrier();

  for (int t = 0;; ++t) {
    const bool lastT = (t == ntiles - 1);
    int m0n = 0, n0n = 0;
    const char* aS2 = aS;
    const char* bS2 = bS;
    if (!lastT) {
      tilecoord(bid + 256 * (t + 1), m0n, n0n);
      aS2 = (const char*)Xb + (size_t)(m0n + srow) * 1536 + scol;
      bS2 = (const char*)Wb + (size_t)(n0n + srow) * 1536 + scol;
    }

    for (int i = 0; i < 6; ++i) {
      const int kb1 = i * 256 + 128;           // kt 2i+1 (in-tile always)
      const bool ib = (i == 5);                // boundary iter
      const bool stg = !(ib && lastT);         // stage kt+2/kt+3 at all?
      const char* pA = ib ? aS2 : aS;          // sources for kt 2i+2 / 2i+3
      const char* pB = ib ? bS2 : bS;
      const int kA = ib ? 0 : i * 256 + 256;

      short8 a[4][2], b[4][2];
      // ---- p0: read buf0 A f0-3 + B g0-1; stage kt(2i+1) A1   [close: no barrier]
      RDA4(AE, 0); RDB2(BE, 0);
      STAGE(AO + 16384, aS + 128 * 1536, kb1);
      PH_OPEN; MF16(0, 0); PH_CLOSE_NB;
      // ---- p1: read buf0 B g2-3; stage kt(2i+1) B0            [close: no barrier]
      RDB2(BE, 2);
      STAGE(BO, bS, kb1);
      PH_OPEN; MF16(0, 2); PH_CLOSE_NB;
      // ---- p2: read buf0 A f4-7; stage kt(2i+1) B1            [close KEPT: AE restaged p3]
      RDA4(AE, 4);
      STAGE(BO + 16384, bS + 128 * 1536, kb1);
      PH_OPEN; MF16(4, 0); PH_CLOSE;
      // ---- p3: stage kt(2i+2) A0; MFMA Q11; counted wait publishes buf1
      if (stg) { STAGE(AE, pA, kA); }
      PH_OPEN; MF16(4, 2);
      __builtin_amdgcn_s_setprio(0);
      if (stg) { asm volatile("s_waitcnt vmcnt(2)" ::: "memory"); }
      else     { asm volatile("s_waitcnt vmcnt(0)" ::: "memory"); }
      __builtin_amdgcn_s_barrier();
      // ---- p4: read buf1 A f0-3 + B g0-1; stage kt(2i+2) A1   [close: no barrier]
      RDA4(AO, 0); RDB2(BO, 0);
      if (stg) { STAGE(AE + 16384, pA + 128 * 1536, kA); }
      PH_OPEN; MF16(0, 0); PH_CLOSE_NB;
      // ---- p5: read buf1 B g2-3; stage kt(2i+2) B0            [close: no barrier]
      RDB2(BO, 2);
      if (stg) { STAGE(BE, pB, kA); }
      PH_OPEN; MF16(0, 2); PH_CLOSE_NB;
      // ---- p6: read buf1 A f4-7; stage kt(2i+2) B1            [close KEPT: AO restaged p7]
      RDA4(AO, 4);
      if (stg) { STAGE(BE + 16384, pB + 128 * 1536, kA); }
      PH_OPEN; MF16(4, 0); PH_CLOSE;
      // ---- p7: stage kt(2i+3) A0; MFMA Q11; counted wait publishes buf0
      if (stg) { STAGE(AO, pA, kA + 128); }
      PH_OPEN; MF16(4, 2);
      __builtin_amdgcn_s_setprio(0);
      if (stg) { asm volatile("s_waitcnt vmcnt(2)" ::: "memory"); }
      __builtin_amdgcn_s_barrier();
    }

    // per-tile epilogue (global stores only; LDS untouched; buf0 for next tile
    // already staged at p3-p6 and published by p7's vmcnt+barrier)
#pragma unroll
    for (int f = 0; f < 8; ++f) {
      int row = m0 + wr * 128 + f * 16 + ldiv * 4;
#pragma unroll
      for (int g = 0; g < 4; ++g) {
        int col = n0 + wc * 64 + g * 16 + lmod;
        float bs = bias[col];
#pragma unroll
        for (int rr = 0; rr < 4; ++rr)
          QKV[(size_t)(row + rr) * 2304 + col] = f2bf(acc[f][g][rr] + bs);
      }
    }
    if (lastT) break;
#pragma unroll
    for (int f = 0; f < 8; ++f)
#pragma unroll
      for (int g = 0; g < 4; ++g)
        acc[f][g] = f32x4{0.f, 0.f, 0.f, 0.f};
    m0 = m0n; n0 = n0n; aS = aS2; bS = bS2;
  }
}

// ---------------- fused MLP: layer1 MFMA GEMM (BK=64, swizzled) + layers 2/3 from LDS ----------------
__global__ __launch_bounds__(256) void gemm_mlp(const ushort* __restrict__ QKV,
                                                const ushort* __restrict__ W1p,
                                                const float* __restrict__ b1p,
                                                const float* __restrict__ W2,
                                                const float* __restrict__ b2,
                                                const float* __restrict__ W3,
                                                const float* __restrict__ b3,
                                                float* __restrict__ SAMPLE) {
  __shared__ char smem[39704];
  float* sW2 = (float*)(smem + 24576);
  float* sW3 = (float*)(smem + 38976);
  float* sb2 = (float*)(smem + 39456);
  float* sb3 = (float*)(smem + 39696);
  const int tid = threadIdx.x;
  const int lane = tid & 63;
  const int wv = tid >> 6;
  const int p0 = blockIdx.x * 128;
  const int lmod = lane & 15, ldiv = lane >> 4;

  for (int i = tid; i < 3600; i += 256) sW2[i] = W2[i];
  for (int i = tid; i < 120; i += 256) sW3[i] = W3[i];
  if (tid < 60) sb2[tid] = b2[tid];
  if (tid < 2) sb3[tid] = b3[tid];

  f32x4 acc[2][4] = {};

  const int srw = lane >> 3;
  const int scol = (((lane & 7) ^ srw) << 4);
  const char* gA[4];
#pragma unroll
  for (int c = 0; c < 4; ++c) {
    int p = p0 + c * 32 + wv * 8 + srw;
    int gr = (p / 196) * 197 + 1 + (p % 196);
    gA[c] = (const char*)QKV + (size_t)gr * 4608 + scol;
  }
  const char* gB[2];
#pragma unroll
  for (int c = 0; c < 2; ++c) {
    int r = c * 32 + wv * 8 + srw;
    gB[c] = (const char*)W1p + (size_t)r * 3072 + scol;
  }

  const int offA0 = (wv * 32 + lmod) * 128;
  const int offA1 = (wv * 32 + 16 + lmod) * 128;
  const int cs0 = (ldiv * 16) ^ ((lmod & 7) << 4);
  const int cs1 = (64 + ldiv * 16) ^ ((lmod & 7) << 4);

  for (int k0 = 0; k0 < 1536; k0 += 64) {
    int kb = k0 * 2;
#pragma unroll
    for (int c = 0; c < 4; ++c)
      async16(smem + c * 4096 + wv * 1024, gA[c] + kb);
#pragma unroll
    for (int c = 0; c < 2; ++c)
      async16(smem + 16384 + c * 4096 + wv * 1024, gB[c] + kb);
    __syncthreads();

    short8 a[2][2], b[4][2];
    a[0][0] = *(const short8*)(smem + offA0 + cs0);
    a[0][1] = *(const short8*)(smem + offA0 + cs1);
    a[1][0] = *(const short8*)(smem + offA1 + cs0);
    a[1][1] = *(const short8*)(smem + offA1 + cs1);
#pragma unroll
    for (int j = 0; j < 4; ++j) {
      int ob = 16384 + (j * 16 + lmod) * 128;
      b[j][0] = *(const short8*)(smem + ob + cs0);
      b[j][1] = *(const short8*)(smem + ob + cs1);
    }
#pragma unroll
    for (int i = 0; i < 2; ++i)
#pragma unroll
      for (int j = 0; j < 4; ++j) {
        acc[i][j] = __builtin_amdgcn_mfma_f32_16x16x32_bf16(a[i][0], b[j][0], acc[i][j], 0, 0, 0);
        acc[i][j] = __builtin_amdgcn_mfma_f32_16x16x32_bf16(a[i][1], b[j][1], acc[i][j], 0, 0, 0);
      }
    __syncthreads();
  }

  // layer-1 epilogue -> LDS H tile [128][66] bf16 (staging area is dead now)
  ushort* Hs = (ushort*)smem;
#pragma unroll
  for (int i = 0; i < 2; ++i) {
    int lrow = wv * 32 + i * 16 + ldiv * 4;
#pragma unroll
    for (int j = 0; j < 4; ++j) {
      int col = j * 16 + lmod;
      float bs = b1p[col];
#pragma unroll
      for (int rr = 0; rr < 4; ++rr) {
        float v = fmaxf(acc[i][j][rr] + bs, 0.f);
        Hs[(lrow + rr) * 66 + col] = f2bf(v);
      }
    }
  }
  __syncthreads();

  // layers 2+3: 2 threads per position (30 output neurons each), combine via shfl
  const int plocal = tid >> 1;
  const int half = tid & 1;
  const uint32_t* hrow = (const uint32_t*)(Hs + plocal * 66);
  float h[60];
#pragma unroll
  for (int i = 0; i < 30; ++i) {
    uint32_t u = hrow[i];
    h[2 * i] = bf2f((ushort)(u & 0xffffu));
    h[2 * i + 1] = bf2f((ushort)(u >> 16));
  }
  float s0 = 0.f, s1 = 0.f;
  const int obase = half * 30;
  for (int oo = 0; oo < 30; ++oo) {
    int o = obase + oo;
    float a = sb2[o];
    const float4* wrow = (const float4*)(sW2 + o * 60);
#pragma unroll
    for (int k = 0; k < 15; ++k) {
      float4 w4 = wrow[k];
      a += h[4 * k] * w4.x + h[4 * k + 1] * w4.y + h[4 * k + 2] * w4.z + h[4 * k + 3] * w4.w;
    }
    a = fmaxf(a, 0.f);
    s0 += a * sW3[o];
    s1 += a * sW3[60 + o];
  }
  s0 += __shfl_xor(s0, 1, 64);
  s1 += __shfl_xor(s1, 1, 64);
  if (half == 0) {
    int p = p0 + plocal;  // < 50176 (392*128 exact)
    SAMPLE[2 * p]     = 1.f / (1.f + __expf(-(s0 + sb3[0])));
    SAMPLE[2 * p + 1] = 1.f / (1.f + __expf(-(s1 + sb3[1])));
  }
}

// ---------------- fused grid-sample + attention: one wave per output row ----------------
// R11-exact scalar form (measured best; R13's uint2/float4 vectorization was -5us).
__global__ __launch_bounds__(256) void sample_attn(const ushort* __restrict__ QKV,
                                                   const float* __restrict__ SAMPLE,
                                                   float* __restrict__ OUT) {
  int tid = threadIdx.x, lane = tid & 63, wv = tid >> 6;
  // bijective XCD swizzle (12608 = 8*1576): same-batch blocks share an XCD L2
  int orig = blockIdx.x;
  int nw = (orig & 7) * 1576 + (orig >> 3);
  int pos = nw * 4 + wv;  // < 50432
  int b = pos / 197, s = pos % 197;

  const uint32_t* qrow = (const uint32_t*)(QKV + (size_t)pos * 2304);
  float qv[12];
#pragma unroll
  for (int j = 0; j < 6; ++j) {
    uint32_t u = qrow[lane + j * 64];
    qv[2 * j] = bf2f((ushort)(u & 0xffffu));
    qv[2 * j + 1] = bf2f((ushort)(u >> 16));
  }

  float sk[12], sv[12];
#pragma unroll
  for (int j = 0; j < 12; ++j) { sk[j] = 0.f; sv[j] = 0.f; }

  if (s == 0) {
#pragma unroll
    for (int j = 0; j < 12; ++j) { sk[j] = 1.f; sv[j] = 1.f; }
  } else {
    int g = s - 1;
    int t0 = 2 * g, t1 = 2 * g + 1;
    const float* smp = SAMPLE + (size_t)b * 392;
    float gx = (t0 < 196) ? smp[2 * t0] : smp[2 * (t0 - 196) + 1];
    float gy = (t1 < 196) ? smp[2 * t1] : smp[2 * (t1 - 196) + 1];
    float ix = ((gx + 1.f) * 14.f - 1.f) * 0.5f;
    float iy = ((gy + 1.f) * 14.f - 1.f) * 0.5f;
    float fx0 = floorf(ix), fy0 = floorf(iy);
    float wx1 = ix - fx0, wx0 = 1.f - wx1;
    float wy1 = iy - fy0, wy0 = 1.f - wy1;
    int x0 = (int)fx0, x1 = x0 + 1, y0 = (int)fy0, y1 = y0 + 1;
    float w[4] = {wy0 * wx0, wy0 * wx1, wy1 * wx0, wy1 * wx1};
    int xs[4] = {x0, x1, x0, x1};
    int ys[4] = {y0, y0, y1, y1};
#pragma unroll
    for (int c = 0; c < 4; ++c) {
      bool valid = (xs[c] >= 0) && (xs[c] <= 13) && (ys[c] >= 0) && (ys[c] <= 13);
      float wc = valid ? w[c] : 0.f;
      int xc = min(max(xs[c], 0), 13);
      int yc = min(max(ys[c], 0), 13);
      const uint32_t* krow =
          (const uint32_t*)(QKV + ((size_t)(b * 197 + 1 + yc * 14 + xc) * 2304 + 768));
      const uint32_t* vrow = krow + 384;
#pragma unroll
      for (int j = 0; j < 6; ++j) {
        uint32_t ku = krow[lane + j * 64];
        uint32_t vu = vrow[lane + j * 64];
        sk[2 * j]     += wc * bf2f((ushort)(ku & 0xffffu));
        sk[2 * j + 1] += wc * bf2f((ushort)(ku >> 16));
        sv[2 * j]     += wc * bf2f((ushort)(vu & 0xffffu));
        sv[2 * j + 1] += wc * bf2f((ushort)(vu >> 16));
      }
    }
  }

  float part = 0.f;
#pragma unroll
  for (int j = 0; j < 12; ++j) part += sk[j] * qv[j];
#pragma unroll
  for (int m = 1; m < 64; m <<= 1) part += __shfl_xor(part, m, 64);
  float sig = 1.f / (1.f + __expf(-TEMP * part));

  float* orow = OUT + (size_t)pos * 768;
#pragma unroll
  for (int j = 0; j < 6; ++j) {
    f32x2 o;
    o.x = sig * sv[2 * j];
    o.y = sig * sv[2 * j + 1];
    __builtin_nontemporal_store(o, (f32x2*)(orow + 2 * lane + 128 * j));
  }
}

extern "C" void kernel_launch(void* const* d_in, const int* in_sizes, int n_in,
                              void* d_out, int out_size, void* d_ws, size_t ws_size,
                              hipStream_t stream) {
  const float* x  = (const float*)d_in[0];
  const float* Wq = (const float*)d_in[2];
  const float* bq = (const float*)d_in[3];
  const float* Wk = (const float*)d_in[4];
  const float* bk = (const float*)d_in[5];
  const float* Wv = (const float*)d_in[6];
  const float* bv = (const float*)d_in[7];
  const float* W1 = (const float*)d_in[8];
  const float* b1 = (const float*)d_in[9];
  const float* W2 = (const float*)d_in[10];
  const float* b2 = (const float*)d_in[11];
  const float* W3 = (const float*)d_in[12];
  const float* b3 = (const float*)d_in[13];
  float* out = (float*)d_out;

  char* ws = (char*)d_ws;
  ushort* x_bf = (ushort*)ws;   ws += 77463552;   // 50432*768*2
  ushort* qkv = (ushort*)ws;    ws += 232390656;  // 50432*2304*2
  ushort* wqkv = (ushort*)ws;   ws += 3538944;    // 2304*768*2
  ushort* w1p = (ushort*)ws;    ws += 196608;     // 64*1536*2
  float* biasq = (float*)ws;    ws += 9216;       // 2304*4
  float* b1p = (float*)ws;      ws += 256;        // 64*4
  float* sample = (float*)ws;   ws += 401408;     // 50176*2*4

  convert_all<<<2048, 256, 0, stream>>>(x, x_bf, Wq, Wk, Wv, bq, bk, bv, W1, b1,
                                        wqkv, w1p, biasq, b1p);
  gemm_qkv<<<256, 512, 0, stream>>>(x_bf, wqkv, biasq, qkv);  // persistent, 12 barriers/kt
  gemm_mlp<<<392, 256, 0, stream>>>(qkv, w1p, b1p, W2, b2, W3, b3, sample);
  sample_attn<<<12608, 256, 0, stream>>>(qkv, sample, out);
}